// Round 2
// baseline (4397.622 us; speedup 1.0000x reference)
//
#include <hip/hip_runtime.h>
#include <hip/hip_cooperative_groups.h>
#include <math.h>

namespace cg = cooperative_groups;

#define H 1536
#define E 512
#define T 48
#define S 32
#define V 128
#define NB 256
#define BT 768   // 12 waves
#define JPB 6    // H / NB
#define ROWS 24  // 4*JPB

__device__ __forceinline__ float sigf(float x) { return 1.0f / (1.0f + expf(-x)); }

// ws layout (floats): h1[H] | h2[H] | xw1[V*4H] (biases folded) | logits[S]
__global__ __launch_bounds__(BT, 3) void nas_persist(
    const int* __restrict__ input_id, const float* __restrict__ emb,
    const float* __restrict__ Wih1, const float* __restrict__ Whh1,
    const float* __restrict__ bih1, const float* __restrict__ bhh1,
    const float* __restrict__ Wih2, const float* __restrict__ Whh2,
    const float* __restrict__ bih2, const float* __restrict__ bhh2,
    const float* __restrict__ Wout, const float* __restrict__ bout,
    float* __restrict__ out, float* __restrict__ ws)
{
    cg::grid_group grid = cg::this_grid();
    const int b = blockIdx.x, tid = threadIdx.x;
    const int wave = tid >> 6, lane = tid & 63;

    float* h1 = ws;
    float* h2 = ws + H;
    float* xw1 = ws + 2 * H;
    float* logits = ws + 2 * H + (size_t)V * 4 * H;

    __shared__ float gacc1[ROWS], gacc2[ROWS], g2f[ROWS], bsum2[ROWS];
    __shared__ float c1s[JPB], c2s[JPB];
    __shared__ float red[12];
    __shared__ int xid_s;

    // ---------------- prologue ----------------
    {
        int gid = b * BT + tid;
        if (gid < 2 * H) ws[gid] = 0.0f;        // h1 = h2 = 0
        if (tid < JPB) { c1s[tid] = 0.f; c2s[tid] = 0.f; }
        if (tid < ROWS) {
            gacc1[tid] = 0.f;                   // W_hh1 @ 0 = 0 for t=0
            int r = (tid / JPB) * H + b * JPB + (tid % JPB);
            bsum2[tid] = bih2[r] + bhh2[r];
        }
        if (tid == 0) xid_s = *input_id;

        // xw1[v][r] = dot(W_ih1[r], emb[v]) + bih1[r] + bhh1[r]
        for (int k = wave; k < ROWS; k += 12) {
            int r = (k / JPB) * H + b * JPB + (k % JPB);
            const float4* wrow = (const float4*)(Wih1 + (size_t)r * E);
            float4 wa = wrow[lane], wb = wrow[lane + 64];
            float bsum = bih1[r] + bhh1[r];
            const float4* e4 = (const float4*)emb;
            for (int v = 0; v < V; ++v) {
                float4 ea = e4[v * (E / 4) + lane], eb = e4[v * (E / 4) + lane + 64];
                float acc = wa.x * ea.x + wa.y * ea.y + wa.z * ea.z + wa.w * ea.w
                          + wb.x * eb.x + wb.y * eb.y + wb.z * eb.z + wb.w * eb.w;
#pragma unroll
                for (int off = 32; off; off >>= 1) acc += __shfl_down(acc, off);
                if (lane == 0) xw1[(size_t)v * 4 * H + r] = acc + bsum;
            }
        }
    }
    grid.sync();

    for (int t = 0; t < T; ++t) {
        // ---------------- phase A ----------------
        if (t > 0) {
            if (wave == 0) {
                float z = (lane < S) ? logits[lane] : -1e30f;
                float v = z; int idx = (lane < S) ? lane : 64 + lane;
#pragma unroll
                for (int off = 32; off; off >>= 1) {
                    float ov = __shfl_xor(v, off); int oi = __shfl_xor(idx, off);
                    if (ov > v || (ov == v && oi < idx)) { v = ov; idx = oi; }
                }
                float e = (lane < S) ? expf(z - v) : 0.f;
#pragma unroll
                for (int off = 32; off; off >>= 1) e += __shfl_xor(e, off);
                if (lane == 0) xid_s = ((t - 1) & 3) * S + idx;
                if (b == 0 && lane < S) out[(size_t)(t - 1) * S + lane] = z - v - logf(e);
            }
            __syncthreads();
        }
        // finish cell1 pointwise (gate order i,f,g,o)
        if (tid < JPB) {
            int j = b * JPB + tid;
            const float* xr = xw1 + (size_t)xid_s * 4 * H;
            float gi = gacc1[tid]           + xr[j];
            float gf = gacc1[JPB + tid]     + xr[H + j];
            float gg = gacc1[2 * JPB + tid] + xr[2 * H + j];
            float go = gacc1[3 * JPB + tid] + xr[3 * H + j];
            float cn = sigf(gf) * c1s[tid] + sigf(gi) * tanhf(gg);
            c1s[tid] = cn;
            h1[j] = sigf(go) * tanhf(cn);
        }
        // W_hh2 @ h2(t-1) dots
        {
            const float4* h24 = (const float4*)h2;
            for (int k = wave * 2; k < wave * 2 + 2; ++k) {
                int r = (k / JPB) * H + b * JPB + (k % JPB);
                const float4* wr = (const float4*)(Whh2 + (size_t)r * H);
                float acc = 0.f;
#pragma unroll
                for (int i = 0; i < 6; ++i) {
                    float4 a = wr[lane + 64 * i], x = h24[lane + 64 * i];
                    acc += a.x * x.x + a.y * x.y + a.z * x.z + a.w * x.w;
                }
#pragma unroll
                for (int off = 32; off; off >>= 1) acc += __shfl_down(acc, off);
                if (lane == 0) gacc2[k] = acc;
            }
        }
        grid.sync();

        // ---------------- phase B: W_ih2 @ h1 + cell2 pointwise ----------------
        {
            const float4* h14 = (const float4*)h1;
            for (int k = wave * 2; k < wave * 2 + 2; ++k) {
                int r = (k / JPB) * H + b * JPB + (k % JPB);
                const float4* wr = (const float4*)(Wih2 + (size_t)r * H);
                float acc = 0.f;
#pragma unroll
                for (int i = 0; i < 6; ++i) {
                    float4 a = wr[lane + 64 * i], x = h14[lane + 64 * i];
                    acc += a.x * x.x + a.y * x.y + a.z * x.z + a.w * x.w;
                }
#pragma unroll
                for (int off = 32; off; off >>= 1) acc += __shfl_down(acc, off);
                if (lane == 0) g2f[k] = acc + gacc2[k] + bsum2[k];
            }
        }
        __syncthreads();
        if (tid < JPB) {
            float gi = g2f[tid], gf = g2f[JPB + tid];
            float gg = g2f[2 * JPB + tid], go = g2f[3 * JPB + tid];
            float cn = sigf(gf) * c2s[tid] + sigf(gi) * tanhf(gg);
            c2s[tid] = cn;
            h2[b * JPB + tid] = sigf(go) * tanhf(cn);
        }
        grid.sync();

        // ------- phase C: head (blocks 0..31) + W_hh1 @ h1 dots for t+1 -------
        if (b < S) {
            const float2* wo = (const float2*)(Wout + ((size_t)t * S + b) * H);
            const float2* h22 = (const float2*)h2;
            float2 wv = wo[tid], hv = h22[tid];
            float acc = wv.x * hv.x + wv.y * hv.y;
#pragma unroll
            for (int off = 32; off; off >>= 1) acc += __shfl_down(acc, off);
            if (lane == 0) red[wave] = acc;
            __syncthreads();
            if (tid == 0) {
                float s_ = 0.f;
#pragma unroll
                for (int i = 0; i < 12; ++i) s_ += red[i];
                logits[b] = s_ + bout[t * S + b];
            }
        }
        {
            const float4* h14 = (const float4*)h1;
            for (int k = wave * 2; k < wave * 2 + 2; ++k) {
                int r = (k / JPB) * H + b * JPB + (k % JPB);
                const float4* wr = (const float4*)(Whh1 + (size_t)r * H);
                float acc = 0.f;
#pragma unroll
                for (int i = 0; i < 6; ++i) {
                    float4 a = wr[lane + 64 * i], x = h14[lane + 64 * i];
                    acc += a.x * x.x + a.y * x.y + a.z * x.z + a.w * x.w;
                }
#pragma unroll
                for (int off = 32; off; off >>= 1) acc += __shfl_down(acc, off);
                if (lane == 0) gacc1[k] = acc;
            }
        }
        grid.sync();
    }

    // ---------------- epilogue: out row T-1 ----------------
    if (b == 0 && wave == 0) {
        float z = (lane < S) ? logits[lane] : -1e30f;
        float v = z;
#pragma unroll
        for (int off = 32; off; off >>= 1) v = fmaxf(v, __shfl_xor(v, off));
        float e = (lane < S) ? expf(z - v) : 0.f;
#pragma unroll
        for (int off = 32; off; off >>= 1) e += __shfl_xor(e, off);
        if (lane < S) out[(size_t)(T - 1) * S + lane] = z - v - logf(e);
    }
}

extern "C" void kernel_launch(void* const* d_in, const int* in_sizes, int n_in,
                              void* d_out, int out_size, void* d_ws, size_t ws_size,
                              hipStream_t stream) {
    const int*   input_id = (const int*)d_in[0];
    const float* emb  = (const float*)d_in[1];
    const float* Wih1 = (const float*)d_in[2];
    const float* Whh1 = (const float*)d_in[3];
    const float* bih1 = (const float*)d_in[4];
    const float* bhh1 = (const float*)d_in[5];
    const float* Wih2 = (const float*)d_in[6];
    const float* Whh2 = (const float*)d_in[7];
    const float* bih2 = (const float*)d_in[8];
    const float* bhh2 = (const float*)d_in[9];
    const float* Wout = (const float*)d_in[10];
    const float* bout = (const float*)d_in[11];
    float* out = (float*)d_out;
    float* ws  = (float*)d_ws;

    void* args[] = { (void*)&input_id, (void*)&emb,
                     (void*)&Wih1, (void*)&Whh1, (void*)&bih1, (void*)&bhh1,
                     (void*)&Wih2, (void*)&Whh2, (void*)&bih2, (void*)&bhh2,
                     (void*)&Wout, (void*)&bout, (void*)&out, (void*)&ws };
    hipLaunchCooperativeKernel((void*)nas_persist, dim3(NB), dim3(BT), args, 0, stream);
}

// Round 3
// 1858.411 us; speedup vs baseline: 2.3663x; 2.3663x over previous
//
#include <hip/hip_runtime.h>
#include <math.h>

#define H 1536
#define E 512
#define T 48
#define S 32
#define V 128
#define NB 256
#define BT 768     // 12 waves
#define NW 12
#define JPB 6      // H / NB
#define ROWS 24    // 4*JPB gate rows per block

__device__ __forceinline__ float sigf(float x) { return 1.0f / (1.0f + expf(-x)); }
__device__ __forceinline__ float dot4(float4 a, float4 b) {
    return a.x * b.x + a.y * b.y + a.z * b.z + a.w * b.w;
}
__device__ __forceinline__ float wred(float acc) {
#pragma unroll
    for (int off = 32; off; off >>= 1) acc += __shfl_down(acc, off);
    return acc;
}

// Cross-block data: relaxed agent-scope atomics -> sc0/sc1 cache-bypass to the
// coherent point (MALL). Weights stay cached in L2 (no fences, no buffer_inv).
#define GLD(p)    __hip_atomic_load((p), __ATOMIC_RELAXED, __HIP_MEMORY_SCOPE_AGENT)
#define GST(p, v) __hip_atomic_store((p), (v), __ATOMIC_RELAXED, __HIP_MEMORY_SCOPE_AGENT)

// Monotonic-counter grid barrier. __syncthreads() drains each wave's vmcnt
// (s_waitcnt vmcnt(0) before s_barrier), so all of this block's agent-scope
// stores are at the coherence point before the arrive-increment.
__device__ __forceinline__ void gbar(unsigned* cnt, unsigned& gen) {
    __syncthreads();
    gen += NB;
    if (threadIdx.x == 0) {
        __hip_atomic_fetch_add(cnt, 1u, __ATOMIC_RELAXED, __HIP_MEMORY_SCOPE_AGENT);
        while (__hip_atomic_load(cnt, __ATOMIC_RELAXED, __HIP_MEMORY_SCOPE_AGENT) < gen) {
            __builtin_amdgcn_s_sleep(2);
        }
    }
    __syncthreads();
}

__global__ void init_kernel(unsigned* cnt) {
    if (threadIdx.x == 0) *cnt = 0u;
}

// ws layout: [0] barrier counter (unsigned) | pad | h1[H] | h2[H]
__global__ __launch_bounds__(BT, 3) void nas_persist(
    const int* __restrict__ input_id, const float* __restrict__ emb,
    const float* __restrict__ Wih1, const float* __restrict__ Whh1,
    const float* __restrict__ bih1, const float* __restrict__ bhh1,
    const float* __restrict__ Wih2, const float* __restrict__ Whh2,
    const float* __restrict__ bih2, const float* __restrict__ bhh2,
    const float* __restrict__ Wout, const float* __restrict__ bout,
    float* __restrict__ out, float* __restrict__ ws)
{
    const int b = blockIdx.x, tid = threadIdx.x;
    const int wave = tid >> 6, lane = tid & 63;

    unsigned* cnt = (unsigned*)ws;
    float* h1g = ws + 64;
    float* h2g = ws + 64 + H;

    __shared__ float4 lds_emb4[2048];        // 32 KB, prologue only
    __shared__ float  xw1_lds[V * ROWS];     // 12 KB: xw1[v][k], biases folded
    __shared__ float4 lds_h1_4[H / 4];       // 6 KB
    __shared__ float4 lds_h2_4[H / 4];       // 6 KB
    __shared__ float  gacc1[ROWS], g2f[ROWS], bsum2[ROWS], zlog[S];
    __shared__ float  c1s[JPB], c2s[JPB];
    __shared__ int    xid_s;

    float* lds_h1 = (float*)lds_h1_4;
    float* lds_h2 = (float*)lds_h2_4;

    unsigned gen = 0;

    // ---------------- prologue ----------------
    for (int i = tid; i < H; i += BT) lds_h2[i] = 0.0f;   // h2(-1) = 0
    if (tid < JPB) { c1s[tid] = 0.f; c2s[tid] = 0.f; }
    if (tid < ROWS) {
        int r = (tid / JPB) * H + b * JPB + (tid % JPB);
        bsum2[tid] = bih2[r] + bhh2[r];
    }

    // xw1_lds[v][k] = dot(Wih1[r(k)], emb[v]) + bih1 + bhh1 for this block's rows
    {
        const int k0 = wave * 2, k1 = k0 + 1;
        const int r0 = (k0 / JPB) * H + b * JPB + (k0 % JPB);
        const int r1 = (k1 / JPB) * H + b * JPB + (k1 % JPB);
        const float4* w0 = (const float4*)(Wih1 + (size_t)r0 * E);
        const float4* w1 = (const float4*)(Wih1 + (size_t)r1 * E);
        float4 w0a = w0[lane], w0b = w0[lane + 64];
        float4 w1a = w1[lane], w1b = w1[lane + 64];
        float bs0 = bih1[r0] + bhh1[r0];
        float bs1 = bih1[r1] + bhh1[r1];
        for (int ch = 0; ch < 8; ++ch) {               // 16 emb rows per chunk
            const float4* src = (const float4*)(emb + (size_t)ch * 16 * E);
            for (int i = tid; i < 2048; i += BT) lds_emb4[i] = src[i];
            __syncthreads();
            for (int vv = 0; vv < 16; ++vv) {
                float4 ea = lds_emb4[vv * 128 + lane];
                float4 eb = lds_emb4[vv * 128 + 64 + lane];
                float a0 = wred(dot4(w0a, ea) + dot4(w0b, eb));
                float a1 = wred(dot4(w1a, ea) + dot4(w1b, eb));
                if (lane == 0) {
                    int v = ch * 16 + vv;
                    xw1_lds[v * ROWS + k0] = a0 + bs0;
                    xw1_lds[v * ROWS + k1] = a1 + bs1;
                }
            }
            __syncthreads();
        }
    }

    // h1(0) = cell1 with h(-1)=0, c(-1)=0
    if (tid == 0) xid_s = *input_id;
    __syncthreads();
    if (tid < JPB) {
        const float* xr = &xw1_lds[xid_s * ROWS];
        float gi = xr[tid], gg = xr[2 * JPB + tid], go = xr[3 * JPB + tid];
        float cn = sigf(gi) * tanhf(gg);
        c1s[tid] = cn;
        GST(h1g + b * JPB + tid, sigf(go) * tanhf(cn));
    }
    gbar(cnt, gen);

    for (int t = 0; t < T; ++t) {
        // ---------- phase X: all three HxH matvecs + cell2 pointwise ----------
        for (int i = tid; i < H; i += BT) lds_h1[i] = GLD(h1g + i);
        __syncthreads();
        {
            const int k0 = wave * 2, k1 = k0 + 1;
            const int r0 = (k0 / JPB) * H + b * JPB + (k0 % JPB);
            const int r1 = (k1 / JPB) * H + b * JPB + (k1 % JPB);
            const float4* x1 = (const float4*)lds_h1;
            const float4* x2 = (const float4*)lds_h2;

            auto rowdot = [&](const float* Wp, int r, const float4* x) {
                const float4* wr = (const float4*)(Wp + (size_t)r * H);
                float acc = 0.f;
#pragma unroll
                for (int i = 0; i < 6; ++i) acc += dot4(wr[lane + 64 * i], x[lane + 64 * i]);
                return wred(acc);
            };

            float d_ih2_0 = rowdot(Wih2, r0, x1);
            float d_ih2_1 = rowdot(Wih2, r1, x1);
            float d_hh2_0 = rowdot(Whh2, r0, x2);
            float d_hh2_1 = rowdot(Whh2, r1, x2);
            float d_hh1_0 = rowdot(Whh1, r0, x1);   // for cell1 at t+1
            float d_hh1_1 = rowdot(Whh1, r1, x1);
            if (lane == 0) {
                g2f[k0] = d_ih2_0 + d_hh2_0 + bsum2[k0];
                g2f[k1] = d_ih2_1 + d_hh2_1 + bsum2[k1];
                gacc1[k0] = d_hh1_0;
                gacc1[k1] = d_hh1_1;
            }
        }
        __syncthreads();
        if (tid < JPB) {
            float gi = g2f[tid],           gf = g2f[JPB + tid];
            float gg = g2f[2 * JPB + tid], go = g2f[3 * JPB + tid];
            float cn = sigf(gf) * c2s[tid] + sigf(gi) * tanhf(gg);
            c2s[tid] = cn;
            GST(h2g + b * JPB + tid, sigf(go) * tanhf(cn));
        }
        gbar(cnt, gen);

        // ---------- phase Y: redundant head + cell1 pointwise for t+1 ----------
        for (int i = tid; i < H; i += BT) lds_h2[i] = GLD(h2g + i);
        __syncthreads();
        {
            const float4* x2 = (const float4*)lds_h2;
            for (int s = wave; s < S; s += NW) {
                const float4* wo = (const float4*)(Wout + ((size_t)t * S + s) * H);
                float acc = 0.f;
#pragma unroll
                for (int i = 0; i < 6; ++i) acc += dot4(wo[lane + 64 * i], x2[lane + 64 * i]);
                acc = wred(acc);
                if (lane == 0) zlog[s] = acc + bout[t * S + s];
            }
        }
        __syncthreads();
        if (wave == 0) {
            float z = (lane < S) ? zlog[lane] : -1e30f;
            float v = z; int idx = (lane < S) ? lane : 9999;
#pragma unroll
            for (int off = 32; off; off >>= 1) {
                float ov = __shfl_xor(v, off); int oi = __shfl_xor(idx, off);
                if (ov > v || (ov == v && oi < idx)) { v = ov; idx = oi; }
            }
            float e = (lane < S) ? expf(z - v) : 0.f;
#pragma unroll
            for (int off = 32; off; off >>= 1) e += __shfl_xor(e, off);
            if (lane == 0) xid_s = (t & 3) * S + idx;
            if (b == 0 && lane < S) out[(size_t)t * S + lane] = z - v - logf(e);
        }
        __syncthreads();
        if (tid < JPB) {
            const float* xr = &xw1_lds[xid_s * ROWS];
            float gi = gacc1[tid]           + xr[tid];
            float gf = gacc1[JPB + tid]     + xr[JPB + tid];
            float gg = gacc1[2 * JPB + tid] + xr[2 * JPB + tid];
            float go = gacc1[3 * JPB + tid] + xr[3 * JPB + tid];
            float cn = sigf(gf) * c1s[tid] + sigf(gi) * tanhf(gg);
            c1s[tid] = cn;
            GST(h1g + b * JPB + tid, sigf(go) * tanhf(cn));
        }
        gbar(cnt, gen);
    }
}

extern "C" void kernel_launch(void* const* d_in, const int* in_sizes, int n_in,
                              void* d_out, int out_size, void* d_ws, size_t ws_size,
                              hipStream_t stream) {
    const int*   input_id = (const int*)d_in[0];
    const float* emb  = (const float*)d_in[1];
    const float* Wih1 = (const float*)d_in[2];
    const float* Whh1 = (const float*)d_in[3];
    const float* bih1 = (const float*)d_in[4];
    const float* bhh1 = (const float*)d_in[5];
    const float* Wih2 = (const float*)d_in[6];
    const float* Whh2 = (const float*)d_in[7];
    const float* bih2 = (const float*)d_in[8];
    const float* bhh2 = (const float*)d_in[9];
    const float* Wout = (const float*)d_in[10];
    const float* bout = (const float*)d_in[11];
    float* out = (float*)d_out;
    float* ws  = (float*)d_ws;

    init_kernel<<<1, 64, 0, stream>>>((unsigned*)ws);

    void* args[] = { (void*)&input_id, (void*)&emb,
                     (void*)&Wih1, (void*)&Whh1, (void*)&bih1, (void*)&bhh1,
                     (void*)&Wih2, (void*)&Whh2, (void*)&bih2, (void*)&bhh2,
                     (void*)&Wout, (void*)&bout, (void*)&out, (void*)&ws };
    hipLaunchCooperativeKernel((void*)nas_persist, dim3(NB), dim3(BT), args, 0, stream);
}

// Round 4
// 1440.907 us; speedup vs baseline: 3.0520x; 1.2898x over previous
//
#include <hip/hip_runtime.h>
#include <math.h>

#define H 1536
#define E 512
#define T 48
#define S 32
#define V 128
#define NB 256
#define BT 768     // 12 waves
#define NW 12
#define JPB 6      // H / NB
#define ROWS 24    // 4*JPB gate rows per block

__device__ __forceinline__ float sigf(float x) { return 1.0f / (1.0f + expf(-x)); }
__device__ __forceinline__ float dot4(float4 a, float4 b) {
    return a.x * b.x + a.y * b.y + a.z * b.z + a.w * b.w;
}
__device__ __forceinline__ float wred(float acc) {
#pragma unroll
    for (int off = 32; off; off >>= 1) acc += __shfl_down(acc, off);
    return acc;
}

// Cross-block data: relaxed agent-scope atomics -> cache-bypass to the coherent
// point (MALL). Weights stay cached in L2/L3 (no fences, no buffer_inv).
#define GLD(p)    __hip_atomic_load((p), __ATOMIC_RELAXED, __HIP_MEMORY_SCOPE_AGENT)
#define GST(p, v) __hip_atomic_store((p), (v), __ATOMIC_RELAXED, __HIP_MEMORY_SCOPE_AGENT)

// Atomic-free master-poller grid barrier.
// __syncthreads() drains each wave's vmcnt (compiler emits s_waitcnt vmcnt(0)
// before s_barrier), so this block's agent-scope data stores are at the
// coherence point before the arrival-flag store. No RMW contention: arrivals
// are parallel plain stores to distinct words; block 0 wave 0 polls them.
__device__ __forceinline__ void gbar(unsigned* flags, unsigned* rel, unsigned& gen) {
    __syncthreads();
    gen++;
    if (blockIdx.x == 0) {
        if (threadIdx.x < 64) {
            const int base = threadIdx.x * 4;
            for (;;) {
                unsigned a0 = (base == 0) ? gen : GLD(&flags[base + 0]);
                unsigned a1 = GLD(&flags[base + 1]);
                unsigned a2 = GLD(&flags[base + 2]);
                unsigned a3 = GLD(&flags[base + 3]);
                bool ok = (a0 >= gen) && (a1 >= gen) && (a2 >= gen) && (a3 >= gen);
                if (__all(ok)) break;
                __builtin_amdgcn_s_sleep(2);
            }
            if (threadIdx.x == 0) GST(rel, gen);
        }
    } else {
        if (threadIdx.x == 0) {
            GST(&flags[blockIdx.x], gen);
            while (GLD(rel) < gen) __builtin_amdgcn_s_sleep(2);
        }
    }
    __syncthreads();
}

__global__ void init_kernel(unsigned* u) {
    if (threadIdx.x < 384) u[threadIdx.x] = 0u;   // release + flags
}

// ws layout (32-bit words): [0] release | [64..320) flags | [384) h1[H] | h2[H]
__global__ __launch_bounds__(BT, 3) void nas_persist(
    const int* __restrict__ input_id, const float* __restrict__ emb,
    const float* __restrict__ Wih1, const float* __restrict__ Whh1,
    const float* __restrict__ bih1, const float* __restrict__ bhh1,
    const float* __restrict__ Wih2, const float* __restrict__ Whh2,
    const float* __restrict__ bih2, const float* __restrict__ bhh2,
    const float* __restrict__ Wout, const float* __restrict__ bout,
    float* __restrict__ out, float* __restrict__ ws)
{
    const int b = blockIdx.x, tid = threadIdx.x;
    const int wave = tid >> 6, lane = tid & 63;

    unsigned* rel   = (unsigned*)ws;
    unsigned* flags = (unsigned*)ws + 64;
    float* h1g = ws + 384;
    float* h2g = ws + 384 + H;

    __shared__ float4 lds_emb4[2048];        // 32 KB, prologue only
    __shared__ float  xw1_lds[V * ROWS];     // 12 KB: xw1[v][k], biases folded
    __shared__ float4 lds_h1_4[H / 4];       // 6 KB
    __shared__ float4 lds_h2_4[H / 4];       // 6 KB
    __shared__ float  gacc1[ROWS], g2f[ROWS], bsum2[ROWS], zlog[S];
    __shared__ float  c1s[JPB], c2s[JPB];
    __shared__ int    xid_s;

    float* lds_h1 = (float*)lds_h1_4;
    float* lds_h2 = (float*)lds_h2_4;

    unsigned gen = 0;

    // ---------------- prologue ----------------
    for (int i = tid; i < H; i += BT) lds_h2[i] = 0.0f;   // h2(-1) = 0
    if (tid < JPB) { c1s[tid] = 0.f; c2s[tid] = 0.f; }
    if (tid < ROWS) {
        int r = (tid / JPB) * H + b * JPB + (tid % JPB);
        bsum2[tid] = bih2[r] + bhh2[r];
    }

    // xw1_lds[v][k] = dot(Wih1[r(k)], emb[v]) + bih1 + bhh1 for this block's rows
    {
        const int k0 = wave * 2, k1 = k0 + 1;
        const int r0 = (k0 / JPB) * H + b * JPB + (k0 % JPB);
        const int r1 = (k1 / JPB) * H + b * JPB + (k1 % JPB);
        const float4* w0 = (const float4*)(Wih1 + (size_t)r0 * E);
        const float4* w1 = (const float4*)(Wih1 + (size_t)r1 * E);
        float4 w0a = w0[lane], w0b = w0[lane + 64];
        float4 w1a = w1[lane], w1b = w1[lane + 64];
        float bs0 = bih1[r0] + bhh1[r0];
        float bs1 = bih1[r1] + bhh1[r1];
        for (int ch = 0; ch < 8; ++ch) {               // 16 emb rows per chunk
            const float4* src = (const float4*)(emb + (size_t)ch * 16 * E);
            for (int i = tid; i < 2048; i += BT) lds_emb4[i] = src[i];
            __syncthreads();
            for (int vv = 0; vv < 16; ++vv) {
                float4 ea = lds_emb4[vv * 128 + lane];
                float4 eb = lds_emb4[vv * 128 + 64 + lane];
                float a0 = wred(dot4(w0a, ea) + dot4(w0b, eb));
                float a1 = wred(dot4(w1a, ea) + dot4(w1b, eb));
                if (lane == 0) {
                    int v = ch * 16 + vv;
                    xw1_lds[v * ROWS + k0] = a0 + bs0;
                    xw1_lds[v * ROWS + k1] = a1 + bs1;
                }
            }
            __syncthreads();
        }
    }

    // h1(0) = cell1 with h(-1)=0, c(-1)=0
    if (tid == 0) xid_s = *input_id;
    __syncthreads();
    if (tid < JPB) {
        const float* xr = &xw1_lds[xid_s * ROWS];
        float gi = xr[tid], gg = xr[2 * JPB + tid], go = xr[3 * JPB + tid];
        float cn = sigf(gi) * tanhf(gg);
        c1s[tid] = cn;
        GST(h1g + b * JPB + tid, sigf(go) * tanhf(cn));
    }
    gbar(flags, rel, gen);

    for (int t = 0; t < T; ++t) {
        // ---------- phase X: all three HxH matvecs + cell2 pointwise ----------
        for (int i = tid; i < H; i += BT) lds_h1[i] = GLD(h1g + i);
        __syncthreads();
        {
            const int k0 = wave * 2, k1 = k0 + 1;
            const int r0 = (k0 / JPB) * H + b * JPB + (k0 % JPB);
            const int r1 = (k1 / JPB) * H + b * JPB + (k1 % JPB);
            const float4* x1 = (const float4*)lds_h1;
            const float4* x2 = (const float4*)lds_h2;

            auto rowdot = [&](const float* Wp, int r, const float4* x) {
                const float4* wr = (const float4*)(Wp + (size_t)r * H);
                float acc = 0.f;
#pragma unroll
                for (int i = 0; i < 6; ++i) acc += dot4(wr[lane + 64 * i], x[lane + 64 * i]);
                return wred(acc);
            };

            float d_ih2_0 = rowdot(Wih2, r0, x1);
            float d_ih2_1 = rowdot(Wih2, r1, x1);
            float d_hh2_0 = rowdot(Whh2, r0, x2);
            float d_hh2_1 = rowdot(Whh2, r1, x2);
            float d_hh1_0 = rowdot(Whh1, r0, x1);   // for cell1 at t+1
            float d_hh1_1 = rowdot(Whh1, r1, x1);
            if (lane == 0) {
                g2f[k0] = d_ih2_0 + d_hh2_0 + bsum2[k0];
                g2f[k1] = d_ih2_1 + d_hh2_1 + bsum2[k1];
                gacc1[k0] = d_hh1_0;
                gacc1[k1] = d_hh1_1;
            }
        }
        __syncthreads();
        if (tid < JPB) {
            float gi = g2f[tid],           gf = g2f[JPB + tid];
            float gg = g2f[2 * JPB + tid], go = g2f[3 * JPB + tid];
            float cn = sigf(gf) * c2s[tid] + sigf(gi) * tanhf(gg);
            c2s[tid] = cn;
            GST(h2g + b * JPB + tid, sigf(go) * tanhf(cn));
        }
        gbar(flags, rel, gen);

        // ---------- phase Y: redundant head + cell1 pointwise for t+1 ----------
        for (int i = tid; i < H; i += BT) lds_h2[i] = GLD(h2g + i);
        __syncthreads();
        {
            const float4* x2 = (const float4*)lds_h2;
            for (int s = wave; s < S; s += NW) {
                const float4* wo = (const float4*)(Wout + ((size_t)t * S + s) * H);
                float acc = 0.f;
#pragma unroll
                for (int i = 0; i < 6; ++i) acc += dot4(wo[lane + 64 * i], x2[lane + 64 * i]);
                acc = wred(acc);
                if (lane == 0) zlog[s] = acc + bout[t * S + s];
            }
        }
        __syncthreads();
        if (wave == 0) {
            float z = (lane < S) ? zlog[lane] : -1e30f;
            float v = z; int idx = (lane < S) ? lane : 9999;
#pragma unroll
            for (int off = 32; off; off >>= 1) {
                float ov = __shfl_xor(v, off); int oi = __shfl_xor(idx, off);
                if (ov > v || (ov == v && oi < idx)) { v = ov; idx = oi; }
            }
            float e = (lane < S) ? expf(z - v) : 0.f;
#pragma unroll
            for (int off = 32; off; off >>= 1) e += __shfl_xor(e, off);
            if (lane == 0) xid_s = (t & 3) * S + idx;
            if (b == 0 && lane < S) out[(size_t)t * S + lane] = z - v - logf(e);
        }
        __syncthreads();
        if (tid < JPB) {
            const float* xr = &xw1_lds[xid_s * ROWS];
            float gi = gacc1[tid]           + xr[tid];
            float gf = gacc1[JPB + tid]     + xr[JPB + tid];
            float gg = gacc1[2 * JPB + tid] + xr[2 * JPB + tid];
            float go = gacc1[3 * JPB + tid] + xr[3 * JPB + tid];
            float cn = sigf(gf) * c1s[tid] + sigf(gi) * tanhf(gg);
            c1s[tid] = cn;
            GST(h1g + b * JPB + tid, sigf(go) * tanhf(cn));
        }
        gbar(flags, rel, gen);
    }
}

extern "C" void kernel_launch(void* const* d_in, const int* in_sizes, int n_in,
                              void* d_out, int out_size, void* d_ws, size_t ws_size,
                              hipStream_t stream) {
    const int*   input_id = (const int*)d_in[0];
    const float* emb  = (const float*)d_in[1];
    const float* Wih1 = (const float*)d_in[2];
    const float* Whh1 = (const float*)d_in[3];
    const float* bih1 = (const float*)d_in[4];
    const float* bhh1 = (const float*)d_in[5];
    const float* Wih2 = (const float*)d_in[6];
    const float* Whh2 = (const float*)d_in[7];
    const float* bih2 = (const float*)d_in[8];
    const float* bhh2 = (const float*)d_in[9];
    const float* Wout = (const float*)d_in[10];
    const float* bout = (const float*)d_in[11];
    float* out = (float*)d_out;
    float* ws  = (float*)d_ws;

    init_kernel<<<1, 512, 0, stream>>>((unsigned*)ws);

    void* args[] = { (void*)&input_id, (void*)&emb,
                     (void*)&Wih1, (void*)&Whh1, (void*)&bih1, (void*)&bhh1,
                     (void*)&Wih2, (void*)&Whh2, (void*)&bih2, (void*)&bhh2,
                     (void*)&Wout, (void*)&bout, (void*)&out, (void*)&ws };
    hipLaunchCooperativeKernel((void*)nas_persist, dim3(NB), dim3(BT), args, 0, stream);
}